// Round 10
// baseline (185.807 us; speedup 1.0000x reference)
//
#include <hip/hip_runtime.h>
#include <hip/hip_bf16.h>
#include <stdint.h>

// Problem constants (fixed by reference)
#define LQ   2048
#define NH   16
#define DD   128
#define NB   2
#define QBLK 128          // q-rows per block strip (8 waves x 16)
#define KBLK 128          // K/V tile rows
#define NQT  (LQ/QBLK)    // 16 strips; paired qt <-> 15-qt for balance
#define ROWSTR (NH*DD)    // 2048 floats between consecutive seq rows
#define KTILE (KBLK*132)  // 16896 shorts per K tile buffer
#define VTILE (64*256)    // 16384 shorts per V tile buffer (64 subtiles 16x16)

typedef float f32x4 __attribute__((ext_vector_type(4)));
typedef short s16x4 __attribute__((ext_vector_type(4)));
typedef short s16x8 __attribute__((ext_vector_type(8)));

// scalar cast -> compiler packs into v_cvt_pk_bf16_f32 (m240)
__device__ __forceinline__ short f2bf(float f) {
  union { __hip_bfloat16 h; short s; } u;
  u.h = __float2bfloat16(f);
  return u.s;
}

__device__ __forceinline__ s16x4 cvt4(f32x4 x) {
  s16x4 r; r[0] = f2bf(x[0]); r[1] = f2bf(x[1]); r[2] = f2bf(x[2]); r[3] = f2bf(x[3]);
  return r;
}

__device__ __forceinline__ uint32_t lds_u32(const void* p) {
  return (uint32_t)(uint64_t)p;
}

// hardware transpose read (verified config): addr = subtile_base + 8*lane over a
// contiguous 128B-aligned [16][16] bf16 subtile -> lane gets col l15, rows 4*lhi+j
__device__ __forceinline__ s16x4 tr16(uint32_t addr) {
  s16x4 d;
  asm volatile("ds_read_b64_tr_b16 %0, %1" : "=v"(d) : "v"(addr) : "memory");
  return d;
}

struct KStage { f32x4 k[8]; };
struct VStage { f32x4 v[8]; };

__device__ __forceinline__ KStage loadK(const float* __restrict__ Kg, int s0, int tid) {
  KStage st;
  const int rk = tid >> 5;          // 0..15
  const int c4 = tid & 31;
#pragma unroll
  for (int j = 0; j < 8; ++j)
    st.k[j] = *(const f32x4*)(Kg + (size_t)(s0 + rk + 16 * j) * ROWSTR + 4 * c4);
  return st;
}

__device__ __forceinline__ void writeK(short* Kb, const KStage& st, int tid) {
  const int rk = tid >> 5;
  const int c4 = tid & 31;
  // K row-major padded 132 (measured conflict-free)
#pragma unroll
  for (int j = 0; j < 8; ++j)
    *(s16x4*)&Kb[(rk + 16 * j) * 132 + 4 * c4] = cvt4(st.k[j]);
}

__device__ __forceinline__ VStage loadV(const float* __restrict__ Vg, int s0, int tid) {
  VStage st;
#pragma unroll
  for (int p = 0; p < 8; ++p) {
    const int g = tid + 512 * p;                // 0..4095, bijective
    const int rv = (g & 3) | ((g >> 7) << 2);   // 0..127
    const int cv = (g >> 2) & 31;
    st.v[p] = *(const f32x4*)(Vg + (size_t)(s0 + rv) * ROWSTR + 4 * cv);
  }
  return st;
}

__device__ __forceinline__ void writeV(short* Vb, const VStage& st, int tid) {
#pragma unroll
  for (int p = 0; p < 8; ++p) {
    const int g = tid + 512 * p;
    const int rv = (g & 3) | ((g >> 7) << 2);
    const int cv = (g >> 2) & 31;
    const int sub = (rv >> 4) * 8 + (cv >> 2);   // 0..63 (measured-clean map)
    *(s16x4*)&Vb[sub * 256 + (rv & 15) * 16 + 4 * (cv & 3)] = cvt4(st.v[p]);
  }
}

__global__ __launch_bounds__(512, 1) void qattn_fwd(
    const float* __restrict__ keys, const float* __restrict__ values,
    float* __restrict__ out)
{
  __shared__ short SM[2 * KTILE + 2 * VTILE];   // 133,120 B -> 1 block/CU

  const int tid  = threadIdx.x;
  const int wid  = tid >> 6;      // 0..7 waves
  const int lane = tid & 63;
  const int l15  = lane & 15;
  const int lhi  = lane >> 4;     // 0..3

  // proven R4 map: 256 blocks, two complementary strips each (17 tiles/block)
  const int wg   = blockIdx.x;
  const int bh   = wg & 31;
  const int pair = wg >> 5;             // 0..7
  const int b    = bh >> 4;
  const int h    = bh & 15;

  const float* Kg = keys   + ((size_t)b * LQ * ROWSTR) + (size_t)h * DD;
  const float* Vg = values + ((size_t)b * LQ * ROWSTR) + (size_t)h * DD;
  float*       Og = out    + ((size_t)b * LQ * ROWSTR) + (size_t)h * DD;

  // logits * (0.5/sqrt(128)) * log2(e); folded into Q fragments.
  // quantum_score cancels in softmax (uniform shift).
  const float CS = 0.5f * 0.08838834764831845f * 1.4426950408889634f;

  for (int sp = 0; sp < 2; ++sp) {
    const int qt = sp ? (NQT - 1 - pair) : pair;
    const int q0 = qt * QBLK;
    const int nt = qt + 1;              // 128-row tiles covering s <= q0+127

    // ---- Q fragments (Q := values rows), CS pre-folded, f32 -> bf16 regs ----
    const int qg = q0 + wid * 16 + l15; // this lane's q-row
    const float* Qrow = Vg + (size_t)qg * ROWSTR;
    s16x8 qf[4];
#pragma unroll
    for (int c = 0; c < 4; ++c) {
      f32x4 lo = *(const f32x4*)(Qrow + 32 * c + 4 * lhi);
      f32x4 hi = *(const f32x4*)(Qrow + 32 * c + 16 + 4 * lhi);
      lo *= CS; hi *= CS;
      qf[c] = __builtin_shufflevector(cvt4(lo), cvt4(hi), 0, 1, 2, 3, 4, 5, 6, 7);
    }

    f32x4 o[8];
#pragma unroll
    for (int i = 0; i < 8; ++i) o[i] = f32x4{0.f, 0.f, 0.f, 0.f};
    float m  = -1e30f;   // running max (exp2-logit units), keyed by q = l15
    float ll = 0.0f;

    // ---- prologue: stage tile 0 into buf 0 ----
    {
      KStage kst = loadK(Kg, 0, tid);
      VStage vst = loadV(Vg, 0, tid);
      writeK(SM, kst, tid);
      writeV(SM + 2 * KTILE, vst, tid);
    }
    __syncthreads();

    for (int t = 0; t < nt; ++t) {
      const int cur = t & 1;
      const int s0  = t * KBLK;
      const bool more = (t + 1) < nt;
      const bool diag = (t == nt - 1);           // only last tile crosses diagonal

      const short* Kb = SM + cur * KTILE;
      const short* Vb = SM + 2 * KTILE + cur * VTILE;
      short* Kn = SM + (cur ^ 1) * KTILE;
      short* Vn = SM + 2 * KTILE + (cur ^ 1) * VTILE;

      // issue next K loads early; they land during QK^T
      KStage kst;
      if (more) kst = loadK(Kg, (t + 1) * KBLK, tid);

      // ---- QK^T swapped: sT[sb] = K_sb · Q^T -> S^T[s][q] ----
      f32x4 sT[8];
#pragma unroll
      for (int sb = 0; sb < 8; ++sb) sT[sb] = f32x4{0.f, 0.f, 0.f, 0.f};
      __builtin_amdgcn_s_setprio(1);
#pragma unroll
      for (int sb = 0; sb < 8; ++sb) {
        if (!diag || sb <= wid) {                // wave-uniform diagonal skip
#pragma unroll
          for (int c = 0; c < 4; ++c) {
            s16x4 a  = *(const s16x4*)&Kb[(sb * 16 + l15) * 132 + 32 * c + 4 * lhi];
            s16x4 bb = *(const s16x4*)&Kb[(sb * 16 + l15) * 132 + 32 * c + 16 + 4 * lhi];
            s16x8 kf = __builtin_shufflevector(a, bb, 0, 1, 2, 3, 4, 5, 6, 7);
            sT[sb] = __builtin_amdgcn_mfma_f32_16x16x32_bf16(kf, qf[c], sT[sb], 0, 0, 0);
          }
        }
      }
      __builtin_amdgcn_s_setprio(0);

      // next V loads; land during softmax/PV
      VStage vst;
      if (more) vst = loadV(Vg, (t + 1) * KBLK, tid);
      if (more) writeK(Kn, kst, tid);            // K regs retire here

      // ---- online softmax: lane owns q=l15, s = s0 + sb*16 + 4*lhi + r ----
      if (diag) {                                // causal mask (incl. skipped sb)
#pragma unroll
        for (int sb = 0; sb < 8; ++sb)
#pragma unroll
          for (int r = 0; r < 4; ++r)
            if (s0 + sb * 16 + 4 * lhi + r > qg) sT[sb][r] = -1e30f;
      }
      // tree max over 32 values (depth 5), then 2 cross-lane combines
      float mx[16];
#pragma unroll
      for (int i = 0; i < 16; ++i) mx[i] = fmaxf(sT[i >> 1][(i & 1) * 2], sT[i >> 1][(i & 1) * 2 + 1]);
#pragma unroll
      for (int i = 0; i < 8; ++i) mx[i] = fmaxf(mx[2 * i], mx[2 * i + 1]);
#pragma unroll
      for (int i = 0; i < 4; ++i) mx[i] = fmaxf(mx[2 * i], mx[2 * i + 1]);
      float tm = fmaxf(fmaxf(mx[0], mx[1]), fmaxf(mx[2], mx[3]));
      tm = fmaxf(tm, __shfl_xor(tm, 16));
      tm = fmaxf(tm, __shfl_xor(tm, 32));

      // defer-max (T13): only rescale when max grew past THR=8 (exp2 units)
      if (!__all(tm - m <= 8.0f)) {
        const float mn = fmaxf(m, tm);
        const float alpha = exp2f(m - mn);
        m = mn;
        float ar[4];
#pragma unroll
        for (int r = 0; r < 4; ++r) ar[r] = __shfl(alpha, 4 * lhi + r);
#pragma unroll
        for (int df = 0; df < 8; ++df)
#pragma unroll
          for (int r = 0; r < 4; ++r) o[df][r] *= ar[r];
        ll *= alpha;
      }
      float rs = 0.f;
      s16x8 pf[4];
#pragma unroll
      for (int ks = 0; ks < 4; ++ks)
#pragma unroll
        for (int sb = 0; sb < 2; ++sb)
#pragma unroll
          for (int r = 0; r < 4; ++r) {
            float p = exp2f(sT[2 * ks + sb][r] - m);
            rs += p;
            pf[ks][sb * 4 + r] = f2bf(p);
          }

      // ---- PV via hardware transpose reads, four 32-row k-slots ----
      const uint32_t vbase = lds_u32(Vb) + 8u * (uint32_t)lane;
#pragma unroll
      for (int ks = 0; ks < 4; ++ks) {
        if (!diag || ks <= (wid >> 1)) {         // wave-uniform diagonal skip
          s16x4 vlo[8], vhi[8];
#pragma unroll
          for (int df = 0; df < 8; ++df) {
            vlo[df] = tr16(vbase + 512u * (uint32_t)(16 * ks + df));
            vhi[df] = tr16(vbase + 512u * (uint32_t)(16 * ks + 8 + df));
          }
          asm volatile("s_waitcnt lgkmcnt(0)" ::: "memory");
          __builtin_amdgcn_sched_barrier(0);
          __builtin_amdgcn_s_setprio(1);
#pragma unroll
          for (int df = 0; df < 8; ++df) {
            s16x8 vf = __builtin_shufflevector(vlo[df], vhi[df], 0, 1, 2, 3, 4, 5, 6, 7);
            o[df] = __builtin_amdgcn_mfma_f32_16x16x32_bf16(pf[ks], vf, o[df], 0, 0, 0);
          }
          __builtin_amdgcn_s_setprio(0);
        }
      }

      if (more) writeV(Vn, vst, tid);            // V regs retire here

      // denominator cross-lane combine off the critical path (after PV issue)
      rs += __shfl_xor(rs, 16);
      rs += __shfl_xor(rs, 32);
      ll += rs;

      __syncthreads();                           // single barrier per tile
    }

    // ---- epilogue: O /= l, store f32 (global only; no LDS hazard) ----
    const float linv = 1.0f / ll;
#pragma unroll
    for (int r = 0; r < 4; ++r) {
      const float lr = __shfl(linv, 4 * lhi + r);
      float* orow = Og + (size_t)(q0 + wid * 16 + 4 * lhi + r) * ROWSTR;
#pragma unroll
      for (int df = 0; df < 8; ++df)
        orow[df * 16 + l15] = o[df][r] * lr;
    }
  }
}

extern "C" void kernel_launch(void* const* d_in, const int* in_sizes, int n_in,
                              void* d_out, int out_size, void* d_ws, size_t ws_size,
                              hipStream_t stream) {
  // inputs: 0=queries (dead), 1=keys, 2=values, 3=q_params (dead: softmax shift)
  const float* keys   = (const float*)d_in[1];
  const float* values = (const float*)d_in[2];
  float*       out    = (float*)d_out;
  dim3 grid(NB * NH * (NQT / 2));   // 256 blocks: one per CU, perfectly balanced
  dim3 block(512);
  hipLaunchKernelGGL(qattn_fwd, grid, block, 0, stream, keys, values, out);
}

// Round 11
// 95.126 us; speedup vs baseline: 1.9533x; 1.9533x over previous
//
#include <hip/hip_runtime.h>
#include <hip/hip_bf16.h>
#include <stdint.h>

// Problem constants (fixed by reference)
#define LQ   2048
#define NH   16
#define DD   128
#define NB   2
#define QBLK 128          // rows per block strip (8 waves x 16)
#define KBLK 64           // K/V tile rows
#define NQT  (LQ/QBLK)    // 16 strips; paired qt <-> 15-qt for balance
#define ROWSTR (NH*DD)    // 2048 floats between consecutive seq rows

typedef float f32x4 __attribute__((ext_vector_type(4)));
typedef short s16x4 __attribute__((ext_vector_type(4)));
typedef short s16x8 __attribute__((ext_vector_type(8)));

// scalar cast -> compiler packs into v_cvt_pk_bf16_f32 (m240)
__device__ __forceinline__ short f2bf(float f) {
  union { __hip_bfloat16 h; short s; } u;
  u.h = __float2bfloat16(f);
  return u.s;
}

__device__ __forceinline__ s16x4 cvt4(f32x4 x) {
  s16x4 r; r[0] = f2bf(x[0]); r[1] = f2bf(x[1]); r[2] = f2bf(x[2]); r[3] = f2bf(x[3]);
  return r;
}

__device__ __forceinline__ uint32_t lds_u32(const void* p) {
  return (uint32_t)(uint64_t)p;
}

// hardware transpose read (verified config): addr = subtile_base + 8*lane over a
// contiguous 128B-aligned [16][16] bf16 subtile -> lane gets col l15, rows 4*lhi+j
__device__ __forceinline__ s16x4 tr16(uint32_t addr) {
  s16x4 d;
  asm volatile("ds_read_b64_tr_b16 %0, %1" : "=v"(d) : "v"(addr) : "memory");
  return d;
}

struct Stage { f32x4 k[4]; f32x4 v[4]; };

__device__ __forceinline__ Stage load_tile(const float* __restrict__ Kg,
                                           const float* __restrict__ Vg,
                                           int s0, int tid) {
  Stage st;
  const int rk = tid >> 5;          // 0..15
  const int c4 = tid & 31;
#pragma unroll
  for (int j = 0; j < 4; ++j)
    st.k[j] = *(const f32x4*)(Kg + (size_t)(s0 + rk + 16 * j) * ROWSTR + 4 * c4);
#pragma unroll
  for (int p = 0; p < 4; ++p) {
    const int g = tid + 512 * p;
    const int rv = (g & 3) | ((g >> 7) << 2);   // 0..63, bijective
    const int cv = (g >> 2) & 31;
    st.v[p] = *(const f32x4*)(Vg + (size_t)(s0 + rv) * ROWSTR + 4 * cv);
  }
  return st;
}

__device__ __forceinline__ void write_tile(short* Kb, short* Vb,
                                           const Stage& st, int tid) {
  const int rk = tid >> 5;
  const int c4 = tid & 31;
  // K row-major padded 132 (measured conflict-free)
#pragma unroll
  for (int j = 0; j < 4; ++j)
    *(s16x4*)&Kb[(rk + 16 * j) * 132 + 4 * c4] = cvt4(st.k[j]);
#pragma unroll
  for (int p = 0; p < 4; ++p) {
    const int g = tid + 512 * p;
    const int rv = (g & 3) | ((g >> 7) << 2);
    const int cv = (g >> 2) & 31;
    const int sub = (rv >> 4) * 8 + (cv >> 2);   // s_hi*8 + d_blk, 0..31
    *(s16x4*)&Vb[sub * 256 + (rv & 15) * 16 + 4 * (cv & 3)] = cvt4(st.v[p]);
  }
}

__global__ __launch_bounds__(512, 2) void qattn_fwd(
    const float* __restrict__ keys, const float* __restrict__ values,
    float* __restrict__ out)
{
  __shared__ short K_lds[2][KBLK * 132];   // row-major padded 132 (16.5 KB ea)
  __shared__ short V_lds[2][32 * 256];     // 32x [16][16] subtiles (16 KB ea)

  const int tid  = threadIdx.x;
  const int wid  = tid >> 6;      // 0..7 waves
  const int lane = tid & 63;
  const int l15  = lane & 15;
  const int lhi  = lane >> 4;     // 0..3

  // proven R4 map: 256 blocks, two complementary strips each (34 tiles/block)
  const int wg   = blockIdx.x;
  const int bh   = wg & 31;
  const int pair = wg >> 5;             // 0..7
  const int b    = bh >> 4;
  const int h    = bh & 15;

  const float* Kg = keys   + ((size_t)b * LQ * ROWSTR) + (size_t)h * DD;
  const float* Vg = values + ((size_t)b * LQ * ROWSTR) + (size_t)h * DD;
  float*       Og = out    + ((size_t)b * LQ * ROWSTR) + (size_t)h * DD;

  // logits * (0.5/sqrt(128)) * log2(e); folded into Q fragments.
  // quantum_score cancels in softmax (uniform shift).
  const float CS = 0.5f * 0.08838834764831845f * 1.4426950408889634f;

  for (int sp = 0; sp < 2; ++sp) {
    const int qt = sp ? (NQT - 1 - pair) : pair;
    const int q0 = qt * QBLK;
    const int nt = 2 * qt + 2;            // 64-row tiles covering s <= q0+127

    // ---- Q fragments (Q := values rows), CS pre-folded, f32 -> bf16 regs ----
    const int qg = q0 + wid * 16 + l15;   // this lane's q-row
    const float* Qrow = Vg + (size_t)qg * ROWSTR;
    s16x8 qf[4];
#pragma unroll
    for (int c = 0; c < 4; ++c) {
      f32x4 lo = *(const f32x4*)(Qrow + 32 * c + 4 * lhi);
      f32x4 hi = *(const f32x4*)(Qrow + 32 * c + 16 + 4 * lhi);
      lo *= CS; hi *= CS;
      qf[c] = __builtin_shufflevector(cvt4(lo), cvt4(hi), 0, 1, 2, 3, 4, 5, 6, 7);
    }

    f32x4 o[8];
#pragma unroll
    for (int i = 0; i < 8; ++i) o[i] = f32x4{0.f, 0.f, 0.f, 0.f};
    float m  = -1e30f;   // running max (exp2-logit units), keyed by q = l15
    float ll = 0.0f;
    const int q_wave_hi = q0 + wid * 16 + 15;

    // ---- prologue: stage tile 0 into buf 0 ----
    {
      Stage st = load_tile(Kg, Vg, 0, tid);
      write_tile(K_lds[0], V_lds[0], st, tid);
    }
    __syncthreads();

    for (int t = 0; t < nt; ++t) {
      const int cur = t & 1;
      const int s0  = t * KBLK;

      // issue next tile's global loads early (latency hides under compute)
      Stage st;
      const bool more = (t + 1) < nt;
      if (more) st = load_tile(Kg, Vg, (t + 1) * KBLK, tid);

      if (s0 <= q_wave_hi) {                 // per-wave causal skip
        const short* Kb = K_lds[cur];
        const short* Vb = V_lds[cur];
        // wave-uniform diagonal limits: compute only s-blocks that intersect
        // s <= q_wave_hi (masked products are zero anyway)
        const int sbmax = min(3, (q_wave_hi - s0) >> 4);
        const int ksmax = min(1, (q_wave_hi - s0) >> 5);

        // ---- QK^T swapped: sT[sb] = K_sb · Q^T -> S^T[s][q] ----
        f32x4 sT[4];
#pragma unroll
        for (int sb = 0; sb < 4; ++sb) sT[sb] = f32x4{0.f, 0.f, 0.f, 0.f};
        __builtin_amdgcn_s_setprio(1);
#pragma unroll
        for (int sb = 0; sb < 4; ++sb) {
          if (sb <= sbmax) {
#pragma unroll
            for (int c = 0; c < 4; ++c) {
              s16x4 a  = *(const s16x4*)&Kb[(sb * 16 + l15) * 132 + 32 * c + 4 * lhi];
              s16x4 bb = *(const s16x4*)&Kb[(sb * 16 + l15) * 132 + 32 * c + 16 + 4 * lhi];
              s16x8 kf = __builtin_shufflevector(a, bb, 0, 1, 2, 3, 4, 5, 6, 7);
              sT[sb] = __builtin_amdgcn_mfma_f32_16x16x32_bf16(kf, qf[c], sT[sb], 0, 0, 0);
            }
          }
        }
        __builtin_amdgcn_s_setprio(0);

        // ---- online softmax: lane owns q=l15, s = s0 + sb*16 + 4*lhi + r ----
        if (s0 + KBLK - 1 > qg) {            // diagonal tile: causal mask
#pragma unroll
          for (int sb = 0; sb < 4; ++sb)
#pragma unroll
            for (int r = 0; r < 4; ++r)
              if (s0 + sb * 16 + 4 * lhi + r > qg) sT[sb][r] = -1e30f;
        }
        // tree max (pairs fuse to v_max3), then 2 cross-lane combines
        float m0 = fmaxf(fmaxf(sT[0][0], sT[0][1]), fmaxf(sT[0][2], sT[0][3]));
        float m1 = fmaxf(fmaxf(sT[1][0], sT[1][1]), fmaxf(sT[1][2], sT[1][3]));
        float m2 = fmaxf(fmaxf(sT[2][0], sT[2][1]), fmaxf(sT[2][2], sT[2][3]));
        float m3 = fmaxf(fmaxf(sT[3][0], sT[3][1]), fmaxf(sT[3][2], sT[3][3]));
        float tm = fmaxf(fmaxf(m0, m1), fmaxf(m2, m3));
        tm = fmaxf(tm, __shfl_xor(tm, 16));
        tm = fmaxf(tm, __shfl_xor(tm, 32));

        // defer-max (T13): only rescale when max grew past THR=8 (exp2 units)
        if (!__all(tm - m <= 8.0f)) {
          const float mn = fmaxf(m, tm);
          const float alpha = exp2f(m - mn);
          m = mn;
          float ar[4];
#pragma unroll
          for (int r = 0; r < 4; ++r) ar[r] = __shfl(alpha, 4 * lhi + r);
#pragma unroll
          for (int df = 0; df < 8; ++df)
#pragma unroll
            for (int r = 0; r < 4; ++r) o[df][r] *= ar[r];
          ll *= alpha;
        }
        float rs = 0.f;
        s16x8 pf0, pf1;
#pragma unroll
        for (int sb = 0; sb < 2; ++sb)
#pragma unroll
          for (int r = 0; r < 4; ++r) {
            float p = exp2f(sT[sb][r] - m);
            rs += p;
            pf0[sb * 4 + r] = f2bf(p);
          }
#pragma unroll
        for (int sb = 0; sb < 2; ++sb)
#pragma unroll
          for (int r = 0; r < 4; ++r) {
            float p = exp2f(sT[2 + sb][r] - m);
            rs += p;
            pf1[sb * 4 + r] = f2bf(p);
          }

        // ---- PV via hardware transpose reads, two 32-row k-slots ----
        const uint32_t vbase = lds_u32(Vb) + 8u * (uint32_t)lane;
#pragma unroll
        for (int ks = 0; ks < 2; ++ks) {
          if (ks <= ksmax) {
            s16x4 vlo[8], vhi[8];
#pragma unroll
            for (int df = 0; df < 8; ++df) {
              vlo[df] = tr16(vbase + 512u * (uint32_t)(16 * ks + df));
              vhi[df] = tr16(vbase + 512u * (uint32_t)(16 * ks + 8 + df));
            }
            asm volatile("s_waitcnt lgkmcnt(0)" ::: "memory");
            __builtin_amdgcn_sched_barrier(0);
            const s16x8 pf = ks ? pf1 : pf0;
            __builtin_amdgcn_s_setprio(1);
#pragma unroll
            for (int df = 0; df < 8; ++df) {
              s16x8 vf = __builtin_shufflevector(vlo[df], vhi[df], 0, 1, 2, 3, 4, 5, 6, 7);
              o[df] = __builtin_amdgcn_mfma_f32_16x16x32_bf16(pf, vf, o[df], 0, 0, 0);
            }
            __builtin_amdgcn_s_setprio(0);
          }
        }

        // denominator cross-lane combine off the critical path (after PV issue)
        rs += __shfl_xor(rs, 16);
        rs += __shfl_xor(rs, 32);
        ll += rs;
      }

      // write next tile into the other buffer (compiler inserts vmcnt wait)
      if (more) write_tile(K_lds[cur ^ 1], V_lds[cur ^ 1], st, tid);
      __syncthreads();                       // single barrier per tile
    }

    // ---- epilogue: O /= l, store f32 ----
    const float linv = 1.0f / ll;
#pragma unroll
    for (int r = 0; r < 4; ++r) {
      const float lr = __shfl(linv, 4 * lhi + r);
      float* orow = Og + (size_t)(q0 + wid * 16 + 4 * lhi + r) * ROWSTR;
#pragma unroll
      for (int df = 0; df < 8; ++df)
        orow[df * 16 + l15] = o[df][r] * lr;
    }
  }
}

extern "C" void kernel_launch(void* const* d_in, const int* in_sizes, int n_in,
                              void* d_out, int out_size, void* d_ws, size_t ws_size,
                              hipStream_t stream) {
  // inputs: 0=queries (dead), 1=keys, 2=values, 3=q_params (dead: softmax shift)
  const float* keys   = (const float*)d_in[1];
  const float* values = (const float*)d_in[2];
  float*       out    = (float*)d_out;
  dim3 grid(NB * NH * (NQT / 2));   // 256 blocks: one per CU, perfectly balanced
  dim3 block(512);
  hipLaunchKernelGGL(qattn_fwd, grid, block, 0, stream, keys, values, out);
}

// Round 12
// 86.571 us; speedup vs baseline: 2.1463x; 1.0988x over previous
//
#include <hip/hip_runtime.h>
#include <hip/hip_bf16.h>
#include <stdint.h>

// Problem constants (fixed by reference)
#define LQ   2048
#define NH   16
#define DD   128
#define NB   2
#define QBLK 128          // rows per block strip (8 waves x 16)
#define KBLK 64           // K/V tile rows
#define NQT  (LQ/QBLK)    // 16 strips; paired qt <-> 15-qt for balance
#define ROWSTR (NH*DD)    // 2048 floats between consecutive seq rows

typedef float f32x4 __attribute__((ext_vector_type(4)));
typedef short s16x4 __attribute__((ext_vector_type(4)));
typedef short s16x8 __attribute__((ext_vector_type(8)));

// scalar cast -> compiler packs into v_cvt_pk_bf16_f32 (m240)
__device__ __forceinline__ short f2bf(float f) {
  union { __hip_bfloat16 h; short s; } u;
  u.h = __float2bfloat16(f);
  return u.s;
}

__device__ __forceinline__ s16x4 cvt4(f32x4 x) {
  s16x4 r; r[0] = f2bf(x[0]); r[1] = f2bf(x[1]); r[2] = f2bf(x[2]); r[3] = f2bf(x[3]);
  return r;
}

__device__ __forceinline__ uint32_t lds_u32(const void* p) {
  return (uint32_t)(uint64_t)p;
}

// hardware transpose read (verified config): addr = subtile_base + 8*lane over a
// contiguous 128B-aligned [16][16] bf16 subtile -> lane gets col l15, rows 4*lhi+j
__device__ __forceinline__ s16x4 tr16(uint32_t addr) {
  s16x4 d;
  asm volatile("ds_read_b64_tr_b16 %0, %1" : "=v"(d) : "v"(addr) : "memory");
  return d;
}

struct Stage { f32x4 k[4]; f32x4 v[4]; };

__device__ __forceinline__ Stage load_tile(const float* __restrict__ Kg,
                                           const float* __restrict__ Vg,
                                           int s0, int tid) {
  Stage st;
  const int rk = tid >> 5;          // 0..15
  const int c4 = tid & 31;
#pragma unroll
  for (int j = 0; j < 4; ++j)
    st.k[j] = *(const f32x4*)(Kg + (size_t)(s0 + rk + 16 * j) * ROWSTR + 4 * c4);
#pragma unroll
  for (int p = 0; p < 4; ++p) {
    const int g = tid + 512 * p;
    const int rv = (g & 3) | ((g >> 7) << 2);   // 0..63, bijective
    const int cv = (g >> 2) & 31;
    st.v[p] = *(const f32x4*)(Vg + (size_t)(s0 + rv) * ROWSTR + 4 * cv);
  }
  return st;
}

__device__ __forceinline__ void write_tile(short* Kb, short* Vb,
                                           const Stage& st, int tid) {
  const int rk = tid >> 5;
  const int c4 = tid & 31;
  // K row-major padded 132 (measured conflict-free)
#pragma unroll
  for (int j = 0; j < 4; ++j)
    *(s16x4*)&Kb[(rk + 16 * j) * 132 + 4 * c4] = cvt4(st.k[j]);
#pragma unroll
  for (int p = 0; p < 4; ++p) {
    const int g = tid + 512 * p;
    const int rv = (g & 3) | ((g >> 7) << 2);
    const int cv = (g >> 2) & 31;
    const int sub = (rv >> 4) * 8 + (cv >> 2);   // s_hi*8 + d_blk, 0..31
    *(s16x4*)&Vb[sub * 256 + (rv & 15) * 16 + 4 * (cv & 3)] = cvt4(st.v[p]);
  }
}

__global__ __launch_bounds__(512, 2) void qattn_fwd(
    const float* __restrict__ keys, const float* __restrict__ values,
    float* __restrict__ out)
{
  __shared__ short K_lds[2][KBLK * 132];   // row-major padded 132 (16.5 KB ea)
  __shared__ short V_lds[2][32 * 256];     // 32x [16][16] subtiles (16 KB ea)

  const int tid  = threadIdx.x;
  const int wid  = tid >> 6;      // 0..7 waves
  const int lane = tid & 63;
  const int l15  = lane & 15;
  const int lhi  = lane >> 4;     // 0..3

  // proven R4 map: 256 blocks, two complementary strips each (34 tiles/block)
  const int wg   = blockIdx.x;
  const int bh   = wg & 31;
  const int pair = wg >> 5;             // 0..7
  const int b    = bh >> 4;
  const int h    = bh & 15;

  const float* Kg = keys   + ((size_t)b * LQ * ROWSTR) + (size_t)h * DD;
  const float* Vg = values + ((size_t)b * LQ * ROWSTR) + (size_t)h * DD;
  float*       Og = out    + ((size_t)b * LQ * ROWSTR) + (size_t)h * DD;

  // logits * (0.5/sqrt(128)) * log2(e); folded into Q fragments.
  // quantum_score cancels in softmax (uniform shift).
  const float CS = 0.5f * 0.08838834764831845f * 1.4426950408889634f;

  for (int sp = 0; sp < 2; ++sp) {
    const int qt = sp ? (NQT - 1 - pair) : pair;
    const int q0 = qt * QBLK;
    const int nt = 2 * qt + 2;            // 64-row tiles covering s <= q0+127

    // ---- Q fragments (Q := values rows), CS pre-folded, f32 -> bf16 regs ----
    const int qg = q0 + wid * 16 + l15;   // this lane's q-row
    const float* Qrow = Vg + (size_t)qg * ROWSTR;
    s16x8 qf[4];
#pragma unroll
    for (int c = 0; c < 4; ++c) {
      f32x4 lo = *(const f32x4*)(Qrow + 32 * c + 4 * lhi);
      f32x4 hi = *(const f32x4*)(Qrow + 32 * c + 16 + 4 * lhi);
      lo *= CS; hi *= CS;
      qf[c] = __builtin_shufflevector(cvt4(lo), cvt4(hi), 0, 1, 2, 3, 4, 5, 6, 7);
    }

    f32x4 o[8];
#pragma unroll
    for (int i = 0; i < 8; ++i) o[i] = f32x4{0.f, 0.f, 0.f, 0.f};
    float m  = -1e30f;   // running max (exp2-logit units), keyed by q = l15
    float ll = 0.0f;
    const int q_wave_hi = q0 + wid * 16 + 15;

    // ---- prologue: stage tile 0 into buf 0 ----
    {
      Stage st = load_tile(Kg, Vg, 0, tid);
      write_tile(K_lds[0], V_lds[0], st, tid);
    }
    __syncthreads();

    for (int t = 0; t < nt; ++t) {
      const int cur = t & 1;
      const int s0  = t * KBLK;

      // issue next tile's global loads early (latency hides under compute)
      Stage st;
      const bool more = (t + 1) < nt;
      if (more) st = load_tile(Kg, Vg, (t + 1) * KBLK, tid);

      if (s0 <= q_wave_hi) {                 // per-wave causal skip
        const short* Kb = K_lds[cur];
        const short* Vb = V_lds[cur];

        // ---- QK^T swapped: sT[sb] = K_sb · Q^T -> S^T[s][q] ----
        f32x4 sT[4];
#pragma unroll
        for (int sb = 0; sb < 4; ++sb) sT[sb] = f32x4{0.f, 0.f, 0.f, 0.f};
        __builtin_amdgcn_s_setprio(1);
#pragma unroll
        for (int c = 0; c < 4; ++c) {
#pragma unroll
          for (int sb = 0; sb < 4; ++sb) {
            s16x4 a  = *(const s16x4*)&Kb[(sb * 16 + l15) * 132 + 32 * c + 4 * lhi];
            s16x4 bb = *(const s16x4*)&Kb[(sb * 16 + l15) * 132 + 32 * c + 16 + 4 * lhi];
            s16x8 kf = __builtin_shufflevector(a, bb, 0, 1, 2, 3, 4, 5, 6, 7);
            sT[sb] = __builtin_amdgcn_mfma_f32_16x16x32_bf16(kf, qf[c], sT[sb], 0, 0, 0);
          }
        }
        __builtin_amdgcn_s_setprio(0);

        // ---- hoisted V tr-reads for ks=0: latency hides under softmax ----
        const uint32_t vbase = lds_u32(Vb) + 8u * (uint32_t)lane;
        s16x4 vlo0[8], vhi0[8];
#pragma unroll
        for (int df = 0; df < 8; ++df) {
          vlo0[df] = tr16(vbase + 512u * (uint32_t)df);
          vhi0[df] = tr16(vbase + 512u * (uint32_t)(8 + df));
        }

        // ---- online softmax: lane owns q=l15, s = s0 + sb*16 + 4*lhi + r ----
        if (s0 + KBLK - 1 > qg) {            // diagonal tile: causal mask
#pragma unroll
          for (int sb = 0; sb < 4; ++sb)
#pragma unroll
            for (int r = 0; r < 4; ++r)
              if (s0 + sb * 16 + 4 * lhi + r > qg) sT[sb][r] = -1e30f;
        }
        // tree max (pairs fuse to v_max3), then 2 cross-lane combines
        float m0 = fmaxf(fmaxf(sT[0][0], sT[0][1]), fmaxf(sT[0][2], sT[0][3]));
        float m1 = fmaxf(fmaxf(sT[1][0], sT[1][1]), fmaxf(sT[1][2], sT[1][3]));
        float m2 = fmaxf(fmaxf(sT[2][0], sT[2][1]), fmaxf(sT[2][2], sT[2][3]));
        float m3 = fmaxf(fmaxf(sT[3][0], sT[3][1]), fmaxf(sT[3][2], sT[3][3]));
        float tm = fmaxf(fmaxf(m0, m1), fmaxf(m2, m3));
        tm = fmaxf(tm, __shfl_xor(tm, 16));
        tm = fmaxf(tm, __shfl_xor(tm, 32));

        // defer-max (T13): only rescale when max grew past THR=8 (exp2 units)
        if (!__all(tm - m <= 8.0f)) {
          const float mn = fmaxf(m, tm);
          const float alpha = exp2f(m - mn);
          m = mn;
          float ar[4];
#pragma unroll
          for (int r = 0; r < 4; ++r) ar[r] = __shfl(alpha, 4 * lhi + r);
#pragma unroll
          for (int df = 0; df < 8; ++df)
#pragma unroll
            for (int r = 0; r < 4; ++r) o[df][r] *= ar[r];
          ll *= alpha;
        }
        float rs = 0.f;
        s16x8 pf0, pf1;
#pragma unroll
        for (int sb = 0; sb < 2; ++sb)
#pragma unroll
          for (int r = 0; r < 4; ++r) {
            float p = exp2f(sT[sb][r] - m);
            rs += p;
            pf0[sb * 4 + r] = f2bf(p);
          }
#pragma unroll
        for (int sb = 0; sb < 2; ++sb)
#pragma unroll
          for (int r = 0; r < 4; ++r) {
            float p = exp2f(sT[2 + sb][r] - m);
            rs += p;
            pf1[sb * 4 + r] = f2bf(p);
          }

        // ---- PV ks=0 (tr-reads already in flight) ----
        asm volatile("s_waitcnt lgkmcnt(0)" ::: "memory");
        __builtin_amdgcn_sched_barrier(0);
        __builtin_amdgcn_s_setprio(1);
#pragma unroll
        for (int df = 0; df < 8; ++df) {
          s16x8 vf = __builtin_shufflevector(vlo0[df], vhi0[df], 0, 1, 2, 3, 4, 5, 6, 7);
          o[df] = __builtin_amdgcn_mfma_f32_16x16x32_bf16(pf0, vf, o[df], 0, 0, 0);
        }
        __builtin_amdgcn_s_setprio(0);

        // ---- PV ks=1 ----
        {
          s16x4 vlo1[8], vhi1[8];
#pragma unroll
          for (int df = 0; df < 8; ++df) {
            vlo1[df] = tr16(vbase + 512u * (uint32_t)(16 + df));
            vhi1[df] = tr16(vbase + 512u * (uint32_t)(24 + df));
          }
          asm volatile("s_waitcnt lgkmcnt(0)" ::: "memory");
          __builtin_amdgcn_sched_barrier(0);
          __builtin_amdgcn_s_setprio(1);
#pragma unroll
          for (int df = 0; df < 8; ++df) {
            s16x8 vf = __builtin_shufflevector(vlo1[df], vhi1[df], 0, 1, 2, 3, 4, 5, 6, 7);
            o[df] = __builtin_amdgcn_mfma_f32_16x16x32_bf16(pf1, vf, o[df], 0, 0, 0);
          }
          __builtin_amdgcn_s_setprio(0);
        }

        // denominator cross-lane combine off the critical path (after PV issue)
        rs += __shfl_xor(rs, 16);
        rs += __shfl_xor(rs, 32);
        ll += rs;
      }

      // write next tile into the other buffer (compiler inserts vmcnt wait)
      if (more) write_tile(K_lds[cur ^ 1], V_lds[cur ^ 1], st, tid);
      __syncthreads();                       // single barrier per tile
    }

    // ---- epilogue: O /= l, store f32 ----
    const float linv = 1.0f / ll;
#pragma unroll
    for (int r = 0; r < 4; ++r) {
      const float lr = __shfl(linv, 4 * lhi + r);
      float* orow = Og + (size_t)(q0 + wid * 16 + 4 * lhi + r) * ROWSTR;
#pragma unroll
      for (int df = 0; df < 8; ++df)
        orow[df * 16 + l15] = o[df][r] * lr;
    }
  }
}

extern "C" void kernel_launch(void* const* d_in, const int* in_sizes, int n_in,
                              void* d_out, int out_size, void* d_ws, size_t ws_size,
                              hipStream_t stream) {
  // inputs: 0=queries (dead), 1=keys, 2=values, 3=q_params (dead: softmax shift)
  const float* keys   = (const float*)d_in[1];
  const float* values = (const float*)d_in[2];
  float*       out    = (float*)d_out;
  dim3 grid(NB * NH * (NQT / 2));   // 256 blocks: one per CU, perfectly balanced
  dim3 block(512);
  hipLaunchKernelGGL(qattn_fwd, grid, block, 0, stream, keys, values, out);
}